// Round 14
// baseline (51.072 us; speedup 1.0000x reference)
//
#include <hip/hip_runtime.h>
#include <hip/hip_bf16.h>
#include <math.h>

#define KP   512
#define DD   64
#define BB   4096
#define NTRI 2016

typedef __attribute__((ext_vector_type(8))) short bfrag;    // 8 bf16 (4 VGPRs)
typedef __attribute__((ext_vector_type(4))) float facc4;    // 16x16 MFMA accumulator

// ws layout (bytes):
//   Limg  : KP * 8192   per k: HI bf16 plane only ([e][d], row-swizzled)
//           element (e,d) at u16 index e*64 + (d ^ ((e&7)<<3))
//   wws   : KP * 64 * 4   — MINUS w (used directly as MFMA C operand)
//   biasws: KP * 4
//   mahal : BB * KP * 4

__device__ __forceinline__ void async16(const void* g, void* l) {
    __builtin_amdgcn_global_load_lds(
        (const __attribute__((address_space(1))) unsigned int*)g,
        (__attribute__((address_space(3))) unsigned int*)l, 16, 0, 0);
}

__global__ __launch_bounds__(256) void prep_kernel(
    const float* __restrict__ mu, const float* __restrict__ log_diag,
    const float* __restrict__ log_s, const float* __restrict__ lod,
    unsigned short* __restrict__ Limg, float* __restrict__ wws,
    float* __restrict__ biasws)
{
    const int k = blockIdx.x;
    const int tid = threadIdx.x;
    __shared__ float Lc[64 * 64];   // Lc[e*64 + d] = L[d][e]
    __shared__ float muS[64];
    __shared__ float wp[4][64];

    for (int idx = tid; idx < 4096; idx += 256) Lc[idx] = 0.0f;
    if (tid < 64) muS[tid] = mu[k * 64 + tid];
    __syncthreads();

    if (tid < 64) Lc[tid * 64 + tid] = expf(0.5f * log_diag[k * 64 + tid]);
    for (int t = tid; t < NTRI; t += 256) {
        int i = (int)((1.0f + sqrtf(8.0f * (float)t + 1.0f)) * 0.5f);
        while (i * (i - 1) / 2 > t) --i;
        while ((i + 1) * i / 2 <= t) ++i;
        int j = t - i * (i - 1) / 2;
        Lc[j * 64 + i] = lod[(size_t)k * NTRI + t];   // L[i][j], i>j
    }
    __syncthreads();

    // w_e = sum_{d>=e} mu[d]*L[d][e], 4-way split over 256 threads
    {
        const int e = tid & 63, part = tid >> 6;
        float s = 0.0f;
        for (int d = e + part; d < 64; d += 4)
            s += muS[d] * Lc[e * 64 + d];
        wp[part][e] = s;
    }
    __syncthreads();
    if (tid < 64)
        wws[k * 64 + tid] = -(wp[0][tid] + wp[1][tid] + wp[2][tid] + wp[3][tid]);

    // hi bf16 plane, row-major [e][d], PRE-SWIZZLED (both-sides rule)
    for (int idx = tid; idx < 4096; idx += 256) {
        int e = idx >> 6, d = idx & 63;
        int sw = (e << 6) | (d ^ ((e & 7) << 3));
        __hip_bfloat16 hb = __float2bfloat16(Lc[idx]);
        Limg[(size_t)k * 4096 + sw] = *(unsigned short*)&hb;
    }
    if (tid == 0) {
        float s = log_s[k];
        float sp = (s > 20.0f) ? s : log1pf(expf(s));
        biasws[k] = logf(sp + 1e-8f);
    }
}

// T' = L^T Z^T per k (m97-verified 16x16x32 bf16 convention), hi-only L.
// R13 body with 2 k per barrier-pair (8 phases, 2-buffer 16KB rotation):
// halves sync overhead at constant register profile; still 4 blocks/CU
// (LDS 36.9KB, VGPR+AGPR ~128). Counted vmcnt 4/6/2.
__global__ __launch_bounds__(256) void mahal_kernel(
    const float* __restrict__ z, const unsigned short* __restrict__ Limg,
    const float* __restrict__ wws, float* __restrict__ mahal)
{
    __shared__ __align__(16) char  ldsImg[2][16384];   // 2 bufs x (2 k x 8KB)
    __shared__ __align__(16) float wS[16 * 64];        // -w for the whole kslice

    const int tid  = threadIdx.x;
    const int wave = tid >> 6;
    const int lane = tid & 63;
    const int g    = lane >> 4;
    const int l15  = lane & 15;

    // bijective remap: 1024 blocks = 32 kslices x 32 bblks; same kslice -> same n%8
    const int n      = blockIdx.x;
    const int kslice = (n & 7) + ((n >> 8) << 3);   // [0,32)
    const int bblk   = (n >> 3) & 31;               // [0,32)
    const int k0     = kslice * 16;
    const int bw     = bblk * 128 + wave * 32;

    const char* imgK = (const char*)Limg + (size_t)k0 * 8192;

    // prologue: stage phase 0 (k0,k0+1 -> 16KB) into buf0
#pragma unroll
    for (int p4 = 0; p4 < 4; ++p4) {
        const int cof = p4 * 4096 + wave * 1024;
        async16(imgK + cof + lane * 16, &ldsImg[0][0] + cof);
    }

    for (int i = tid; i < 16 * 64; i += 256) wS[i] = wws[k0 * 64 + i];

    // Z fragments (B operand): col b = l15, d = ds*32 + 8*g + j, hi/lo split
    bfrag zh[2][2], zl[2][2];
#pragma unroll
    for (int bs = 0; bs < 2; ++bs) {
        const float* zp = z + (size_t)(bw + bs * 16 + l15) * 64 + 8 * g;
#pragma unroll
        for (int ds = 0; ds < 2; ++ds) {
            float4 a = *(const float4*)(zp + ds * 32);
            float4 c = *(const float4*)(zp + ds * 32 + 4);
            float vv[8] = {a.x, a.y, a.z, a.w, c.x, c.y, c.z, c.w};
            bfrag th, tl;
#pragma unroll
            for (int j = 0; j < 8; ++j) {
                __hip_bfloat16 hb = __float2bfloat16(vv[j]);
                float hv = __bfloat162float(hb);
                __hip_bfloat16 lb = __float2bfloat16(vv[j] - hv);
                th[j] = *(short*)&hb;
                tl[j] = *(short*)&lb;
            }
            zh[bs][ds] = th;
            zl[bs][ds] = tl;
        }
    }

    const int swz = (l15 & 7) << 4;

    __syncthreads();   // full drain: phase-0 tile + wS published

    for (int p = 0; p < 8; ++p) {
        // barrier 1: all waves done reading buf[(p+1)&1] (phase p-1's buffer)
        __builtin_amdgcn_s_barrier();

        // issue-early: stage phase p+1 (16KB) into the other buffer
        if (p < 7) {
            const char* src = imgK + (size_t)(p + 1) * 16384;
            char* dst = &ldsImg[(p + 1) & 1][0];
#pragma unroll
            for (int p4 = 0; p4 < 4; ++p4) {
                const int cof = p4 * 4096 + wave * 1024;
                async16(src + cof + lane * 16, dst + cof);
            }
        }

        // counted wait for phase p's tile:
        //   p==0: drained by prologue syncthreads; outstanding = stage(1)[4]
        //   1..6: newer = stores(p-1)[2] + stage(p+1)[4] = 6
        //   p==7: newer = stores(6)[2]
        if (p == 0)      asm volatile("s_waitcnt vmcnt(4)" ::: "memory");
        else if (p < 7)  asm volatile("s_waitcnt vmcnt(6)" ::: "memory");
        else             asm volatile("s_waitcnt vmcnt(2)" ::: "memory");
        // barrier 2: publish phase-p tile across waves
        __builtin_amdgcn_s_barrier();

        const char* buf = &ldsImg[p & 1][0];
        float2 sres[2];

#pragma unroll
        for (int k2 = 0; k2 < 2; ++k2) {
            // -w for this k as facc4 (C-layout reg order: e = et*16 + 4*g + r)
            const float* wrow = wS + (p * 2 + k2) * 64;
            facc4 wv[4];
#pragma unroll
            for (int et = 0; et < 4; ++et)
                wv[et] = *(const facc4*)(wrow + et * 16 + 4 * g);

            facc4 acc[4][2];   // [etile][bsub]; first MFMA per acc uses C = wv[et]

            __builtin_amdgcn_s_setprio(1);
#pragma unroll
            for (int ds = 0; ds < 2; ++ds) {
#pragma unroll
                for (int et = 0; et < 4; ++et) {
                    if (et >= 2 && ds == 0) continue;   // triangular skip
                    const bool first = (ds == 0) ? (et < 2) : (et >= 2);
                    const int ao = k2 * 8192 + et * 2048 + l15 * 128
                                 + ((ds * 64 + 16 * g) ^ swz);
                    bfrag lh = *(const bfrag*)(buf + ao);
#pragma unroll
                    for (int bs = 0; bs < 2; ++bs) {
                        acc[et][bs] = __builtin_amdgcn_mfma_f32_16x16x32_bf16(
                            lh, zh[bs][ds], first ? wv[et] : acc[et][bs], 0, 0, 0);
                        acc[et][bs] = __builtin_amdgcn_mfma_f32_16x16x32_bf16(
                            lh, zl[bs][ds], acc[et][bs], 0, 0, 0);
                    }
                }
            }
            __builtin_amdgcn_s_setprio(0);

            // epilogue: acc already holds t - w
#pragma unroll
            for (int bs = 0; bs < 2; ++bs) {
                float p0 = 0.f, p1 = 0.f, p2 = 0.f, p3 = 0.f;
#pragma unroll
                for (int et = 0; et < 4; ++et) {
                    p0 = fmaf(acc[et][bs][0], acc[et][bs][0], p0);
                    p1 = fmaf(acc[et][bs][1], acc[et][bs][1], p1);
                    p2 = fmaf(acc[et][bs][2], acc[et][bs][2], p2);
                    p3 = fmaf(acc[et][bs][3], acc[et][bs][3], p3);
                }
                float s = (p0 + p1) + (p2 + p3);
                s += __shfl_xor(s, 16, 64);
                s += __shfl_xor(s, 32, 64);
                if (k2 == 0) sres[bs].x = s; else sres[bs].y = s;
            }
        }

        // one float2 store (k pair) per (bs, l15)
#pragma unroll
        for (int bs = 0; bs < 2; ++bs) {
            if (g == 0)
                *(float2*)(mahal + (size_t)(bw + bs * 16 + l15) * KP + k0 + 2 * p) = sres[bs];
        }
    }
}

// one wave per batch row; lane owns 8 consecutive k
__global__ __launch_bounds__(256) void softmax_kernel(
    const float* __restrict__ mahal, const float* __restrict__ biasws,
    float* __restrict__ alpha)
{
    const int tid  = threadIdx.x;
    const int lane = tid & 63;
    const int b    = blockIdx.x * 4 + (tid >> 6);

    const float* mrow = mahal + (size_t)b * KP + lane * 8;
    const float* brow = biasws + lane * 8;
    float4 m0 = *(const float4*)(mrow);
    float4 m1 = *(const float4*)(mrow + 4);
    float4 c0 = *(const float4*)(brow);
    float4 c1 = *(const float4*)(brow + 4);

    float la[8];
    la[0] = fmaf(-0.5f, m0.x, c0.x); la[1] = fmaf(-0.5f, m0.y, c0.y);
    la[2] = fmaf(-0.5f, m0.z, c0.z); la[3] = fmaf(-0.5f, m0.w, c0.w);
    la[4] = fmaf(-0.5f, m1.x, c1.x); la[5] = fmaf(-0.5f, m1.y, c1.y);
    la[6] = fmaf(-0.5f, m1.z, c1.z); la[7] = fmaf(-0.5f, m1.w, c1.w);

    float lm = la[0];
#pragma unroll
    for (int j = 1; j < 8; ++j) lm = fmaxf(lm, la[j]);
#pragma unroll
    for (int off = 32; off >= 1; off >>= 1)
        lm = fmaxf(lm, __shfl_xor(lm, off, 64));

    float a[8], s = 0.0f;
#pragma unroll
    for (int j = 0; j < 8; ++j) { a[j] = expf(la[j] - lm); s += a[j]; }
#pragma unroll
    for (int off = 32; off >= 1; off >>= 1)
        s += __shfl_xor(s, off, 64);

    const float r = 1.0f / (s + 1e-8f);
    float4 o0 = {a[0] * r, a[1] * r, a[2] * r, a[3] * r};
    float4 o1 = {a[4] * r, a[5] * r, a[6] * r, a[7] * r};
    float* orow = alpha + (size_t)b * KP + lane * 8;
    *(float4*)(orow)     = o0;
    *(float4*)(orow + 4) = o1;
}

extern "C" void kernel_launch(void* const* d_in, const int* in_sizes, int n_in,
                              void* d_out, int out_size, void* d_ws, size_t ws_size,
                              hipStream_t stream) {
    const float* z        = (const float*)d_in[0];
    const float* mu       = (const float*)d_in[1];
    const float* log_diag = (const float*)d_in[2];
    const float* log_s    = (const float*)d_in[3];
    const float* lod      = (const float*)d_in[4];
    float* out = (float*)d_out;

    char* ws = (char*)d_ws;
    unsigned short* Limg = (unsigned short*)ws;                 // 4 MB (hi only)
    float* wws    = (float*)(ws + (size_t)KP * 8192);           // 128 KB (-w)
    float* biasws = wws + (size_t)KP * 64;                      // 2 KB
    float* mahalws = biasws + KP;                               // 8 MB

    prep_kernel<<<KP, 256, 0, stream>>>(mu, log_diag, log_s, lod, Limg, wws, biasws);
    mahal_kernel<<<1024, 256, 0, stream>>>(z, Limg, wws, mahalws);
    softmax_kernel<<<BB / 4, 256, 0, stream>>>(mahalws, biasws, out);
}

// Round 15
// 46.590 us; speedup vs baseline: 1.0962x; 1.0962x over previous
//
#include <hip/hip_runtime.h>
#include <hip/hip_bf16.h>
#include <math.h>

#define KP   512
#define DD   64
#define BB   4096
#define NTRI 2016

typedef __attribute__((ext_vector_type(8))) short bfrag;    // 8 bf16 (4 VGPRs)
typedef __attribute__((ext_vector_type(4))) float facc4;    // 16x16 MFMA accumulator

// ws layout (bytes):
//   Limg  : KP * 8192   per k: HI bf16 plane only ([e][d], row-swizzled)
//           element (e,d) at u16 index e*64 + (d ^ ((e&7)<<3))
//   wws   : KP * 64 * 4   — MINUS w (used directly as MFMA C operand)
//   biasws: KP * 4
//   mahal : BB * KP * 4

__device__ __forceinline__ void async16(const void* g, void* l) {
    __builtin_amdgcn_global_load_lds(
        (const __attribute__((address_space(1))) unsigned int*)g,
        (__attribute__((address_space(3))) unsigned int*)l, 16, 0, 0);
}

__global__ __launch_bounds__(256) void prep_kernel(
    const float* __restrict__ mu, const float* __restrict__ log_diag,
    const float* __restrict__ log_s, const float* __restrict__ lod,
    unsigned short* __restrict__ Limg, float* __restrict__ wws,
    float* __restrict__ biasws)
{
    const int k = blockIdx.x;
    const int tid = threadIdx.x;
    __shared__ float Lc[64 * 64];   // Lc[e*64 + d] = L[d][e]
    __shared__ float muS[64];
    __shared__ float wp[4][64];

    for (int idx = tid; idx < 4096; idx += 256) Lc[idx] = 0.0f;
    if (tid < 64) muS[tid] = mu[k * 64 + tid];
    __syncthreads();

    if (tid < 64) Lc[tid * 64 + tid] = expf(0.5f * log_diag[k * 64 + tid]);
    for (int t = tid; t < NTRI; t += 256) {
        int i = (int)((1.0f + sqrtf(8.0f * (float)t + 1.0f)) * 0.5f);
        while (i * (i - 1) / 2 > t) --i;
        while ((i + 1) * i / 2 <= t) ++i;
        int j = t - i * (i - 1) / 2;
        Lc[j * 64 + i] = lod[(size_t)k * NTRI + t];   // L[i][j], i>j
    }
    __syncthreads();

    // w_e = sum_{d>=e} mu[d]*L[d][e], 4-way split over 256 threads
    {
        const int e = tid & 63, part = tid >> 6;
        float s = 0.0f;
        for (int d = e + part; d < 64; d += 4)
            s += muS[d] * Lc[e * 64 + d];
        wp[part][e] = s;
    }
    __syncthreads();
    if (tid < 64)
        wws[k * 64 + tid] = -(wp[0][tid] + wp[1][tid] + wp[2][tid] + wp[3][tid]);

    // hi bf16 plane, row-major [e][d], PRE-SWIZZLED (both-sides rule)
    for (int idx = tid; idx < 4096; idx += 256) {
        int e = idx >> 6, d = idx & 63;
        int sw = (e << 6) | (d ^ ((e & 7) << 3));
        __hip_bfloat16 hb = __float2bfloat16(Lc[idx]);
        Limg[(size_t)k * 4096 + sw] = *(unsigned short*)&hb;
    }
    if (tid == 0) {
        float s = log_s[k];
        float sp = (s > 20.0f) ? s : log1pf(expf(s));
        biasws[k] = logf(sp + 1e-8f);
    }
}

// T' = L^T Z^T per k (m97-verified 16x16x32 bf16 convention), hi-only L.
// R13 body (best measured: 46.9us total) with ONE audited change: 4-buffer
// rotation -> ONE s_barrier per phase. Safety: stage(t+2) targets
// buf[(t+2)%4] == buf[(t-2)%4]; its readers finished compute(t-2) before
// reaching barrier(t-1), and the staging wave is past barrier(t-1).
// Counted vmcnt: steady 8 = stores(t-2)2+stage(t+1)2+stores(t-1)2+stage(t+2)2.
__global__ __launch_bounds__(256) void mahal_kernel(
    const float* __restrict__ z, const unsigned short* __restrict__ Limg,
    const float* __restrict__ wws, float* __restrict__ mahal)
{
    __shared__ __align__(16) char  ldsImg[4][8192];    // 4-deep: [64 e-rows][128B]
    __shared__ __align__(16) float wS[16 * 64];        // -w for the whole kslice

    const int tid  = threadIdx.x;
    const int wave = tid >> 6;
    const int lane = tid & 63;
    const int g    = lane >> 4;
    const int l15  = lane & 15;

    // bijective remap: 1024 blocks = 32 kslices x 32 bblks; same kslice -> same n%8
    const int n      = blockIdx.x;
    const int kslice = (n & 7) + ((n >> 8) << 3);   // [0,32)
    const int bblk   = (n >> 3) & 31;               // [0,32)
    const int k0     = kslice * 16;
    const int bw     = bblk * 128 + wave * 32;

    const char* imgK = (const char*)Limg + (size_t)k0 * 8192;

    // prologue: stage tiles 0,1 into bufs 0,1 (2 async16 per tile per thread)
#pragma unroll
    for (int b0 = 0; b0 < 2; ++b0) {
        const char* src = imgK + (size_t)b0 * 8192;
        char* dst = &ldsImg[b0][0];
#pragma unroll
        for (int p = 0; p < 2; ++p) {
            const int cof = p * 4096 + wave * 1024;
            async16(src + cof + lane * 16, dst + cof);
        }
    }

    for (int i = tid; i < 16 * 64; i += 256) wS[i] = wws[k0 * 64 + i];

    // Z fragments (B operand): col b = l15, d = ds*32 + 8*g + j, hi/lo split
    bfrag zh[2][2], zl[2][2];
#pragma unroll
    for (int bs = 0; bs < 2; ++bs) {
        const float* zp = z + (size_t)(bw + bs * 16 + l15) * 64 + 8 * g;
#pragma unroll
        for (int ds = 0; ds < 2; ++ds) {
            float4 a = *(const float4*)(zp + ds * 32);
            float4 c = *(const float4*)(zp + ds * 32 + 4);
            float vv[8] = {a.x, a.y, a.z, a.w, c.x, c.y, c.z, c.w};
            bfrag th, tl;
#pragma unroll
            for (int j = 0; j < 8; ++j) {
                __hip_bfloat16 hb = __float2bfloat16(vv[j]);
                float hv = __bfloat162float(hb);
                __hip_bfloat16 lb = __float2bfloat16(vv[j] - hv);
                th[j] = *(short*)&hb;
                tl[j] = *(short*)&lb;
            }
            zh[bs][ds] = th;
            zl[bs][ds] = tl;
        }
    }

    const int swz = (l15 & 7) << 4;

    __syncthreads();   // one-time full drain: tiles 0,1 + wS published

    for (int t = 0; t < 16; ++t) {
        // issue-early: stage tile t+2 into buf[(t+2)%4] (no pre-barrier needed:
        // readers of that buffer finished at barrier(t-1))
        if (t + 2 < 16) {
            const char* src = imgK + (size_t)(t + 2) * 8192;
            char* dst = &ldsImg[(t + 2) & 3][0];
#pragma unroll
            for (int p = 0; p < 2; ++p) {
                const int cof = p * 4096 + wave * 1024;
                async16(src + cof + lane * 16, dst + cof);
            }
        }

        // counted wait: this wave's tile-t chunks landed (t<=1: pre-drained)
        if (t < 14)       asm volatile("s_waitcnt vmcnt(8)" ::: "memory");
        else if (t == 14) asm volatile("s_waitcnt vmcnt(6)" ::: "memory");
        else              asm volatile("s_waitcnt vmcnt(4)" ::: "memory");
        // single rendezvous: publish tile t; also proves compute(t-1) done everywhere
        __builtin_amdgcn_s_barrier();

        const char* buf = &ldsImg[t & 3][0];

        // -w for this k as facc4 (C-layout reg order: e = et*16 + 4*g + r)
        const float* wrow = wS + t * 64;
        facc4 wv[4];
#pragma unroll
        for (int et = 0; et < 4; ++et)
            wv[et] = *(const facc4*)(wrow + et * 16 + 4 * g);

        facc4 acc[4][2];   // [etile][bsub]; first MFMA per acc uses C = wv[et]

        __builtin_amdgcn_s_setprio(1);
#pragma unroll
        for (int ds = 0; ds < 2; ++ds) {
#pragma unroll
            for (int et = 0; et < 4; ++et) {
                if (et >= 2 && ds == 0) continue;   // triangular: e>=32 needs d>=32 only
                const bool first = (ds == 0) ? (et < 2) : (et >= 2);
                const int ao = et * 2048 + l15 * 128 + ((ds * 64 + 16 * g) ^ swz);
                bfrag lh = *(const bfrag*)(buf + ao);
#pragma unroll
                for (int bs = 0; bs < 2; ++bs) {
                    acc[et][bs] = __builtin_amdgcn_mfma_f32_16x16x32_bf16(
                        lh, zh[bs][ds], first ? wv[et] : acc[et][bs], 0, 0, 0);
                    acc[et][bs] = __builtin_amdgcn_mfma_f32_16x16x32_bf16(
                        lh, zl[bs][ds], acc[et][bs], 0, 0, 0);
                }
            }
        }
        __builtin_amdgcn_s_setprio(0);

        // epilogue: acc already holds t - w
        const int k = k0 + t;
#pragma unroll
        for (int bs = 0; bs < 2; ++bs) {
            float p0 = 0.f, p1 = 0.f, p2 = 0.f, p3 = 0.f;
#pragma unroll
            for (int et = 0; et < 4; ++et) {
                p0 = fmaf(acc[et][bs][0], acc[et][bs][0], p0);
                p1 = fmaf(acc[et][bs][1], acc[et][bs][1], p1);
                p2 = fmaf(acc[et][bs][2], acc[et][bs][2], p2);
                p3 = fmaf(acc[et][bs][3], acc[et][bs][3], p3);
            }
            float s = (p0 + p1) + (p2 + p3);
            s += __shfl_xor(s, 16, 64);
            s += __shfl_xor(s, 32, 64);
            if (g == 0)
                mahal[(size_t)(bw + bs * 16 + l15) * KP + k] = s;
        }
    }
}

// one wave per batch row; lane owns 8 consecutive k
__global__ __launch_bounds__(256) void softmax_kernel(
    const float* __restrict__ mahal, const float* __restrict__ biasws,
    float* __restrict__ alpha)
{
    const int tid  = threadIdx.x;
    const int lane = tid & 63;
    const int b    = blockIdx.x * 4 + (tid >> 6);

    const float* mrow = mahal + (size_t)b * KP + lane * 8;
    const float* brow = biasws + lane * 8;
    float4 m0 = *(const float4*)(mrow);
    float4 m1 = *(const float4*)(mrow + 4);
    float4 c0 = *(const float4*)(brow);
    float4 c1 = *(const float4*)(brow + 4);

    float la[8];
    la[0] = fmaf(-0.5f, m0.x, c0.x); la[1] = fmaf(-0.5f, m0.y, c0.y);
    la[2] = fmaf(-0.5f, m0.z, c0.z); la[3] = fmaf(-0.5f, m0.w, c0.w);
    la[4] = fmaf(-0.5f, m1.x, c1.x); la[5] = fmaf(-0.5f, m1.y, c1.y);
    la[6] = fmaf(-0.5f, m1.z, c1.z); la[7] = fmaf(-0.5f, m1.w, c1.w);

    float lm = la[0];
#pragma unroll
    for (int j = 1; j < 8; ++j) lm = fmaxf(lm, la[j]);
#pragma unroll
    for (int off = 32; off >= 1; off >>= 1)
        lm = fmaxf(lm, __shfl_xor(lm, off, 64));

    float a[8], s = 0.0f;
#pragma unroll
    for (int j = 0; j < 8; ++j) { a[j] = expf(la[j] - lm); s += a[j]; }
#pragma unroll
    for (int off = 32; off >= 1; off >>= 1)
        s += __shfl_xor(s, off, 64);

    const float r = 1.0f / (s + 1e-8f);
    float4 o0 = {a[0] * r, a[1] * r, a[2] * r, a[3] * r};
    float4 o1 = {a[4] * r, a[5] * r, a[6] * r, a[7] * r};
    float* orow = alpha + (size_t)b * KP + lane * 8;
    *(float4*)(orow)     = o0;
    *(float4*)(orow + 4) = o1;
}

extern "C" void kernel_launch(void* const* d_in, const int* in_sizes, int n_in,
                              void* d_out, int out_size, void* d_ws, size_t ws_size,
                              hipStream_t stream) {
    const float* z        = (const float*)d_in[0];
    const float* mu       = (const float*)d_in[1];
    const float* log_diag = (const float*)d_in[2];
    const float* log_s    = (const float*)d_in[3];
    const float* lod      = (const float*)d_in[4];
    float* out = (float*)d_out;

    char* ws = (char*)d_ws;
    unsigned short* Limg = (unsigned short*)ws;                 // 4 MB (hi only)
    float* wws    = (float*)(ws + (size_t)KP * 8192);           // 128 KB (-w)
    float* biasws = wws + (size_t)KP * 64;                      // 2 KB
    float* mahalws = biasws + KP;                               // 8 MB

    prep_kernel<<<KP, 256, 0, stream>>>(mu, log_diag, log_s, lod, Limg, wws, biasws);
    mahal_kernel<<<1024, 256, 0, stream>>>(z, Limg, wws, mahalws);
    softmax_kernel<<<BB / 4, 256, 0, stream>>>(mahalws, biasws, out);
}